// Round 9
// baseline (680.750 us; speedup 1.0000x reference)
//
#include <hip/hip_runtime.h>
#include <hip/hip_bf16.h>

#define N_NODES 262144
#define C_CH 64
#define K_NBR 16
#define NCLS 40

typedef unsigned short ushort_t;
typedef __attribute__((ext_vector_type(8))) short short8;
typedef __attribute__((ext_vector_type(4))) float floatx4;

__device__ __forceinline__ float bu2f(ushort_t u) {
    union { unsigned u32; float f; } v; v.u32 = ((unsigned)u) << 16; return v.f;
}
__device__ __forceinline__ ushort_t f2bu(float f) {
    union { float f; unsigned u; } v; v.f = f;
    unsigned r = v.u + 0x7FFFu + ((v.u >> 16) & 1u);
    return (ushort_t)(r >> 16);
}
__device__ __forceinline__ floatx4 bcast4(float g) {
    floatx4 v; v[0] = g; v[1] = g; v[2] = g; v[3] = g; return v;
}
__device__ __forceinline__ int ldi(const int* p, long i)       { return p[i]; }
__device__ __forceinline__ int ldi(const long long* p, long i) { return (int)p[i]; }

// ---------------- Sniffer: flags[1] = 1 if nbr is int64 ----------------------
__global__ void sniff_kernel(const void* __restrict__ nbr, int* __restrict__ flags) {
    int lane = threadIdx.x;                 // 64 threads
    const int* ni = (const int*)nbr;
    bool zodd = (ni[2 * lane + 1] == 0);    // int64 high words all zero
    unsigned long long mz = __ballot(zodd);
    if (lane == 0) flags[1] = (mz == ~0ULL) ? 1 : 0;
}

// ---------------- Kernel A: CPE depthwise conv3 + residual ------------------
// f32 x -> bf16 h table. One thread = 2 channels (float2) x 4 nodes.
__global__ void cpe_kernel(const float* __restrict__ x,
                           const float* __restrict__ cw,
                           const float* __restrict__ cb,
                           ushort_t* __restrict__ h) {
    int t  = blockIdx.x * 256 + threadIdx.x;   // [0, N/4 * 32)
    int ig = t >> 5;                           // node group (4 nodes)
    int cp = t & 31;                           // channel pair
    int i0 = ig << 2;
    int c0 = cp * 2;
    float w00 = cw[c0*3+0], w01 = cw[c0*3+1], w02 = cw[c0*3+2], b0 = cb[c0];
    float w10 = cw[c0*3+3], w11 = cw[c0*3+4], w12 = cw[c0*3+5], b1 = cb[c0+1];
    float2 v[6];
#pragma unroll
    for (int r = 0; r < 6; ++r) {
        int i = i0 - 1 + r;
        if (i >= 0 && i < N_NODES) v[r] = *(const float2*)(x + (size_t)i * C_CH + c0);
        else                       v[r] = make_float2(0.f, 0.f);
    }
    unsigned* ho = (unsigned*)h;
#pragma unroll
    for (int j = 0; j < 4; ++j) {
        float r0 = v[j+1].x + b0;
        r0 = fmaf(v[j].x, w00, r0); r0 = fmaf(v[j+1].x, w01, r0); r0 = fmaf(v[j+2].x, w02, r0);
        float r1 = v[j+1].y + b1;
        r1 = fmaf(v[j].y, w10, r1); r1 = fmaf(v[j+1].y, w11, r1); r1 = fmaf(v[j+2].y, w12, r1);
        unsigned pack = (unsigned)f2bu(r0) | (((unsigned)f2bu(r1)) << 16);
        ho[((size_t)(i0 + j) * C_CH + c0) >> 1] = pack;
    }
}

// ---------------- Kernel B: gather + max-rel + MFMA proj/head + logsoftmax --
// Wave = 16 nodes/iter. feat rows in per-wave LDS (bf16), proj via
// mfma_f32_16x16x32_bf16 with residual folded into W' = W + [I;0], bias as
// acc-init. h2 LDS round-trip (D-layout -> A-layout), head MFMA, softmax in
// D-layout, then logits staged in LDS and written as one flat coalesced
// 640-float region per wave (fixes round-8's 6x write amplification).
template <typename IT>
__global__ void graph_head_kernel(const int* __restrict__ flags,
                                  const ushort_t* __restrict__ hws,
                                  const IT* __restrict__ nbr,
                                  const float* __restrict__ gw,
                                  const float* __restrict__ gb,
                                  const float* __restrict__ ow,
                                  const float* __restrict__ ob,
                                  float* __restrict__ out) {
    if ((flags[1] != 0) != (sizeof(IT) == 8)) return;

    // per-wave regions; strides padded for bank spread, 16B-aligned
    __shared__ __align__(16) ushort_t sFeat[4][16 * 136];  // 17408 B: feat[m][0..127]
    __shared__ __align__(16) ushort_t sH2[4][16 * 88];     // 11264 B: h2 rows / logit stage
    // total 28672 B -> 5 blocks/CU

    const int lane   = threadIdx.x & 63;
    const int wave   = threadIdx.x >> 6;
    const int lanelo = lane & 15;
    const int quad   = lane >> 4;

    // ---- preload B-fragments into registers (once per wave) ----
    // B-layout: lane holds B[k = quad*8+j][n = lanelo] for each (k-step, n-tile)
    short8 wfrag[4][4];
#pragma unroll
    for (int s = 0; s < 4; ++s)
#pragma unroll
        for (int nt = 0; nt < 4; ++nt) {
            short8 f;
#pragma unroll
            for (int j = 0; j < 8; ++j) {
                int k = s * 32 + quad * 8 + j;
                int n = nt * 16 + lanelo;
                float w = gw[k * C_CH + n];
                if (k == n) w += 1.0f;          // residual folded in: W' = W + [I;0]
                f[j] = (short)f2bu(w);
            }
            wfrag[s][nt] = f;
        }
    short8 ofrag[2][3];
#pragma unroll
    for (int s = 0; s < 2; ++s)
#pragma unroll
        for (int nt = 0; nt < 3; ++nt) {
            short8 f;
#pragma unroll
            for (int j = 0; j < 8; ++j) {
                int k = s * 32 + quad * 8 + j;
                int n = nt * 16 + lanelo;
                float w = (n < NCLS) ? ow[k * NCLS + n] : 0.f;
                f[j] = (short)f2bu(w);
            }
            ofrag[s][nt] = f;
        }
    float gbf[4];
#pragma unroll
    for (int nt = 0; nt < 4; ++nt) gbf[nt] = gb[nt * 16 + lanelo];
    float obf[3];
#pragma unroll
    for (int nt = 0; nt < 3; ++nt) {
        int n = nt * 16 + lanelo;
        obf[nt] = (n < NCLS) ? ob[n] : 0.f;
    }

    const bool ok2 = (lanelo < 8);   // n-tile 2 covers cols 32..47; valid n<40

    // 4096 groups of 64 nodes; grid 2048 -> exactly 2 uniform iterations
    for (int g = blockIdx.x; g < (N_NODES >> 6); g += gridDim.x) {
        const int nb0 = g * 64 + wave * 16;
        ushort_t* feat = &sFeat[wave][0];
        ushort_t* h2w  = &sH2[wave][0];

        // ---- gather + max-rel, lane = channel ----
#pragma unroll
        for (int q = 0; q < 4; ++q) {
            int idxv = ldi(nbr, (long)nb0 * K_NBR + q * 64 + lane);
#pragma unroll
            for (int tt = 0; tt < 4; ++tt) {
                int t = q * 4 + tt;
                ushort_t hu = hws[(size_t)(nb0 + t) * C_CH + lane];
                float hif = bu2f(hu);
                float mx = -1e30f;
#pragma unroll
                for (int k = 0; k < 16; ++k) {
                    int j = __shfl(idxv, tt * 16 + k, 64);
                    mx = fmaxf(mx, bu2f(hws[((size_t)(unsigned)j << 6) + lane]));
                }
                feat[t * 136 + lane]      = hu;             // h part (k=0..63)
                feat[t * 136 + 64 + lane] = f2bu(mx - hif); // rel part (k=64..127)
            }
        }
        __syncthreads();

        // ---- proj: D[16x64] = feat[16x128] @ W' + gb ----
        floatx4 acc[4];
#pragma unroll
        for (int nt = 0; nt < 4; ++nt) acc[nt] = bcast4(gbf[nt]);
#pragma unroll
        for (int s = 0; s < 4; ++s) {
            // A-frag: A[m=lanelo][k = s*32 + quad*8 + j]
            short8 af = *(const short8*)(feat + lanelo * 136 + s * 32 + quad * 8);
#pragma unroll
            for (int nt = 0; nt < 4; ++nt)
                acc[nt] = __builtin_amdgcn_mfma_f32_16x16x32_bf16(af, wfrag[s][nt], acc[nt], 0, 0, 0);
        }
        // D-layout: row m = quad*4+r, col n = nt*16+lanelo -> write h2 rows (bf16)
#pragma unroll
        for (int nt = 0; nt < 4; ++nt)
#pragma unroll
            for (int r = 0; r < 4; ++r)
                h2w[(quad * 4 + r) * 88 + nt * 16 + lanelo] = f2bu(acc[nt][r]);
        __syncthreads();

        // ---- head: L[16x48] = h2[16x64] @ ow (+ ob) ----
        floatx4 accH[3];
#pragma unroll
        for (int nt = 0; nt < 3; ++nt) accH[nt] = bcast4(obf[nt]);
#pragma unroll
        for (int s = 0; s < 2; ++s) {
            short8 hf = *(const short8*)(h2w + lanelo * 88 + s * 32 + quad * 8);
#pragma unroll
            for (int nt = 0; nt < 3; ++nt)
                accH[nt] = __builtin_amdgcn_mfma_f32_16x16x32_bf16(hf, ofrag[s][nt], accH[nt], 0, 0, 0);
        }

        // ---- log-softmax per row; stage logits in LDS (reuse h2 region) ----
        float* fOut = (float*)h2w;   // 640 floats = 2560 B <= 16*88*2 B
#pragma unroll
        for (int r = 0; r < 4; ++r) {
            float v0 = accH[0][r], v1 = accH[1][r];
            float v2 = ok2 ? accH[2][r] : -1e30f;
            float m = fmaxf(fmaxf(v0, v1), v2);
#pragma unroll
            for (int off = 1; off < 16; off <<= 1) m = fmaxf(m, __shfl_xor(m, off, 64));
            float s = __expf(v0 - m) + __expf(v1 - m) + (ok2 ? __expf(v2 - m) : 0.f);
#pragma unroll
            for (int off = 1; off < 16; off <<= 1) s += __shfl_xor(s, off, 64);
            float li = m + __logf(s);
            int rowbase = (quad * 4 + r) * NCLS;
            fOut[rowbase + lanelo]      = v0 - li;
            fOut[rowbase + 16 + lanelo] = v1 - li;
            if (ok2) fOut[rowbase + 32 + lanelo] = v2 - li;
        }
        __syncthreads();

        // ---- flat coalesced write: 640 consecutive floats per wave ----
        float* obase = out + (size_t)nb0 * NCLS;
#pragma unroll
        for (int k = 0; k < 10; ++k)
            obase[k * 64 + lane] = fOut[k * 64 + lane];
    }
}

extern "C" void kernel_launch(void* const* d_in, const int* in_sizes, int n_in,
                              void* d_out, int out_size, void* d_ws, size_t ws_size,
                              hipStream_t stream) {
    const float* x  = (const float*)d_in[0];
    const float* cw = (const float*)d_in[2];
    const float* cb = (const float*)d_in[3];
    const float* gw = (const float*)d_in[4];
    const float* gb = (const float*)d_in[5];
    const float* ow = (const float*)d_in[6];
    const float* ob = (const float*)d_in[7];
    float* out = (float*)d_out;

    int* flags = (int*)d_ws;
    ushort_t* hws = (ushort_t*)((char*)d_ws + 1024);   // N*64 bf16 = 32 MB

    sniff_kernel<<<1, 64, 0, stream>>>(d_in[1], flags);
    // CPE: N/4 node-groups x 32 channel-pairs = 2.1M threads
    cpe_kernel<<<(N_NODES / 4 * 32) / 256, 256, 0, stream>>>(x, cw, cb, hws);
    // Graph+head: 2048 persistent blocks, 2 uniform iterations each
    graph_head_kernel<int><<<2048, 256, 0, stream>>>(
        flags, hws, (const int*)d_in[1], gw, gb, ow, ob, out);
    graph_head_kernel<long long><<<2048, 256, 0, stream>>>(
        flags, hws, (const long long*)d_in[1], gw, gb, ow, ob, out);
}

// Round 10
// 608.495 us; speedup vs baseline: 1.1187x; 1.1187x over previous
//
#include <hip/hip_runtime.h>
#include <hip/hip_bf16.h>

#define N_NODES 262144
#define C_CH 64
#define K_NBR 16
#define NCLS 40

typedef unsigned short ushort_t;
typedef __attribute__((ext_vector_type(8))) short short8;
typedef __attribute__((ext_vector_type(4))) float floatx4;

__device__ __forceinline__ float bu2f(ushort_t u) {
    union { unsigned u32; float f; } v; v.u32 = ((unsigned)u) << 16; return v.f;
}
__device__ __forceinline__ ushort_t f2bu(float f) {
    union { float f; unsigned u; } v; v.f = f;
    unsigned r = v.u + 0x7FFFu + ((v.u >> 16) & 1u);
    return (ushort_t)(r >> 16);
}
__device__ __forceinline__ floatx4 bcast4(float g) {
    floatx4 v; v[0] = g; v[1] = g; v[2] = g; v[3] = g; return v;
}
__device__ __forceinline__ int ldi(const int* p, long i)       { return p[i]; }
__device__ __forceinline__ int ldi(const long long* p, long i) { return (int)p[i]; }

// ---------------- Sniffer: flags[1] = 1 if nbr is int64 ----------------------
__global__ void sniff_kernel(const void* __restrict__ nbr, int* __restrict__ flags) {
    int lane = threadIdx.x;                 // 64 threads
    const int* ni = (const int*)nbr;
    bool zodd = (ni[2 * lane + 1] == 0);    // int64 high words all zero
    unsigned long long mz = __ballot(zodd);
    if (lane == 0) flags[1] = (mz == ~0ULL) ? 1 : 0;
}

// ---------------- Kernel A: CPE depthwise conv3 + residual ------------------
// f32 x -> bf16 h table. One thread = 4 channels (float4) x 4 nodes.
__global__ void cpe_kernel(const float* __restrict__ x,
                           const float* __restrict__ cw,
                           const float* __restrict__ cb,
                           ushort_t* __restrict__ h) {
    int t  = blockIdx.x * 256 + threadIdx.x;   // [0, N/4 * 16)
    int ig = t >> 4;                           // node group (4 nodes)
    int cq = t & 15;                           // channel quad
    int i0 = ig << 2;
    int c0 = cq * 4;
    float w0[4], w1[4], w2[4], bb[4];
#pragma unroll
    for (int j = 0; j < 4; ++j) {
        w0[j] = cw[(c0 + j) * 3 + 0];
        w1[j] = cw[(c0 + j) * 3 + 1];
        w2[j] = cw[(c0 + j) * 3 + 2];
        bb[j] = cb[c0 + j];
    }
    float4 v[6];
#pragma unroll
    for (int r = 0; r < 6; ++r) {
        int i = i0 - 1 + r;
        if (i >= 0 && i < N_NODES) v[r] = *(const float4*)(x + (size_t)i * C_CH + c0);
        else                       v[r] = make_float4(0.f, 0.f, 0.f, 0.f);
    }
#pragma unroll
    for (int j = 0; j < 4; ++j) {
        float a[4] = {v[j].x, v[j].y, v[j].z, v[j].w};
        float b[4] = {v[j+1].x, v[j+1].y, v[j+1].z, v[j+1].w};
        float c[4] = {v[j+2].x, v[j+2].y, v[j+2].z, v[j+2].w};
        unsigned p0 = 0, p1 = 0;
#pragma unroll
        for (int q = 0; q < 4; ++q) {
            float r = b[q] + bb[q];
            r = fmaf(a[q], w0[q], r);
            r = fmaf(b[q], w1[q], r);
            r = fmaf(c[q], w2[q], r);
            unsigned u = (unsigned)f2bu(r);
            if (q < 2) p0 |= u << (q * 16);
            else       p1 |= u << ((q - 2) * 16);
        }
        *(uint2*)(h + (size_t)(i0 + j) * C_CH + c0) = make_uint2(p0, p1);
    }
}

// ---------------- Kernel B: gather + max-rel + MFMA proj/head + logsoftmax --
// Wave = 16 nodes/iter. B-matrices (W' = W + [I;0], O) staged TRANSPOSED in
// block-shared LDS as bf16; fragments ds_read_b128 per use (NO long-lived
// register fragments -> no scratch spills, the round-8/9 killer).
template <typename IT>
__global__ void __launch_bounds__(256, 4)
graph_head_kernel(const int* __restrict__ flags,
                  const ushort_t* __restrict__ hws,
                  const IT* __restrict__ nbr,
                  const float* __restrict__ gw,
                  const float* __restrict__ gb,
                  const float* __restrict__ ow,
                  const float* __restrict__ ob,
                  float* __restrict__ out) {
    if ((flags[1] != 0) != (sizeof(IT) == 8)) return;

    __shared__ __align__(16) ushort_t sWt[64 * 136];       // 17408 B: W'[n][k], k=0..127
    __shared__ __align__(16) ushort_t sOt[48 * 72];        //  6912 B: O[n][k],  k=0..63
    __shared__ __align__(16) ushort_t sFeat[4][16 * 136];  // 17408 B: feat[m][0..127]
    __shared__ __align__(16) ushort_t sH2[4][16 * 88];     // 11264 B: h2 rows / logit stage
    // total ~53 KB -> 3 blocks/CU

    // ---- stage transposed weights (once per block) ----
    for (int t = threadIdx.x; t < 64 * 128; t += 256) {
        int n = t >> 7, k = t & 127;
        float w = gw[k * C_CH + n];
        if (k == n) w += 1.0f;               // residual folded in: W' = W + [I;0]
        sWt[n * 136 + k] = f2bu(w);
    }
    for (int t = threadIdx.x; t < 48 * 64; t += 256) {
        int n = t >> 6, k = t & 63;
        float w = (n < NCLS) ? ow[k * NCLS + n] : 0.f;
        sOt[n * 72 + k] = f2bu(w);
    }
    __syncthreads();

    const int lane   = threadIdx.x & 63;
    const int wave   = threadIdx.x >> 6;
    const int lanelo = lane & 15;
    const int quad   = lane >> 4;

    float gbf[4];
#pragma unroll
    for (int nt = 0; nt < 4; ++nt) gbf[nt] = gb[nt * 16 + lanelo];
    float obf[3];
#pragma unroll
    for (int nt = 0; nt < 3; ++nt) {
        int n = nt * 16 + lanelo;
        obf[nt] = (n < NCLS) ? ob[n] : 0.f;
    }
    const bool ok2 = (lanelo < 8);   // n-tile 2 covers cols 32..47; valid n<40

    // 4096 groups of 64 nodes; grid 2048 -> exactly 2 uniform iterations
    for (int g = blockIdx.x; g < (N_NODES >> 6); g += gridDim.x) {
        const int nb0 = g * 64 + wave * 16;
        ushort_t* feat = &sFeat[wave][0];
        ushort_t* h2w  = &sH2[wave][0];

        // ---- gather + max-rel, lane = channel ----
#pragma unroll
        for (int q = 0; q < 4; ++q) {
            int idxv = ldi(nbr, (long)nb0 * K_NBR + q * 64 + lane);
#pragma unroll
            for (int tt = 0; tt < 4; ++tt) {
                int t = q * 4 + tt;
                ushort_t hu = hws[(size_t)(nb0 + t) * C_CH + lane];
                float hif = bu2f(hu);
                float mx = -1e30f;
#pragma unroll
                for (int k = 0; k < 16; ++k) {
                    int j = __shfl(idxv, tt * 16 + k, 64);
                    mx = fmaxf(mx, bu2f(hws[((size_t)(unsigned)j << 6) + lane]));
                }
                feat[t * 136 + lane]      = hu;             // h part (k=0..63)
                feat[t * 136 + 64 + lane] = f2bu(mx - hif); // rel part (k=64..127)
            }
        }
        __syncthreads();

        // ---- proj: D[16x64] = feat[16x128] @ W' + gb ----
        floatx4 acc[4];
#pragma unroll
        for (int nt = 0; nt < 4; ++nt) acc[nt] = bcast4(gbf[nt]);
#pragma unroll
        for (int s = 0; s < 4; ++s) {
            // A-frag: A[m=lanelo][k = s*32 + quad*8 + j]
            short8 af = *(const short8*)(feat + lanelo * 136 + s * 32 + quad * 8);
#pragma unroll
            for (int nt = 0; nt < 4; ++nt) {
                // B-frag: B[k = s*32 + quad*8 + j][n = nt*16 + lanelo]
                short8 bf = *(const short8*)(sWt + (nt * 16 + lanelo) * 136 + s * 32 + quad * 8);
                acc[nt] = __builtin_amdgcn_mfma_f32_16x16x32_bf16(af, bf, acc[nt], 0, 0, 0);
            }
        }
        // D-layout: row m = quad*4+r, col n = nt*16+lanelo -> write h2 rows (bf16)
#pragma unroll
        for (int nt = 0; nt < 4; ++nt)
#pragma unroll
            for (int r = 0; r < 4; ++r)
                h2w[(quad * 4 + r) * 88 + nt * 16 + lanelo] = f2bu(acc[nt][r]);
        __syncthreads();

        // ---- head: L[16x48] = h2[16x64] @ O (+ ob) ----
        floatx4 accH[3];
#pragma unroll
        for (int nt = 0; nt < 3; ++nt) accH[nt] = bcast4(obf[nt]);
#pragma unroll
        for (int s = 0; s < 2; ++s) {
            short8 hf = *(const short8*)(h2w + lanelo * 88 + s * 32 + quad * 8);
#pragma unroll
            for (int nt = 0; nt < 3; ++nt) {
                short8 bf = *(const short8*)(sOt + (nt * 16 + lanelo) * 72 + s * 32 + quad * 8);
                accH[nt] = __builtin_amdgcn_mfma_f32_16x16x32_bf16(hf, bf, accH[nt], 0, 0, 0);
            }
        }

        // ---- log-softmax per row; stage logits in LDS (reuse h2 region) ----
        float* fOut = (float*)h2w;   // 640 floats = 2560 B <= 16*88*2 B
#pragma unroll
        for (int r = 0; r < 4; ++r) {
            float v0 = accH[0][r], v1 = accH[1][r];
            float v2 = ok2 ? accH[2][r] : -1e30f;
            float m = fmaxf(fmaxf(v0, v1), v2);
#pragma unroll
            for (int off = 1; off < 16; off <<= 1) m = fmaxf(m, __shfl_xor(m, off, 64));
            float s = __expf(v0 - m) + __expf(v1 - m) + (ok2 ? __expf(v2 - m) : 0.f);
#pragma unroll
            for (int off = 1; off < 16; off <<= 1) s += __shfl_xor(s, off, 64);
            float li = m + __logf(s);
            int rowbase = (quad * 4 + r) * NCLS;
            fOut[rowbase + lanelo]      = v0 - li;
            fOut[rowbase + 16 + lanelo] = v1 - li;
            if (ok2) fOut[rowbase + 32 + lanelo] = v2 - li;
        }
        __syncthreads();

        // ---- flat coalesced write: 640 consecutive floats per wave ----
        float* obase = out + (size_t)nb0 * NCLS;
#pragma unroll
        for (int k = 0; k < 10; ++k)
            obase[k * 64 + lane] = fOut[k * 64 + lane];
    }
}

extern "C" void kernel_launch(void* const* d_in, const int* in_sizes, int n_in,
                              void* d_out, int out_size, void* d_ws, size_t ws_size,
                              hipStream_t stream) {
    const float* x  = (const float*)d_in[0];
    const float* cw = (const float*)d_in[2];
    const float* cb = (const float*)d_in[3];
    const float* gw = (const float*)d_in[4];
    const float* gb = (const float*)d_in[5];
    const float* ow = (const float*)d_in[6];
    const float* ob = (const float*)d_in[7];
    float* out = (float*)d_out;

    int* flags = (int*)d_ws;
    ushort_t* hws = (ushort_t*)((char*)d_ws + 1024);   // N*64 bf16 = 32 MB

    sniff_kernel<<<1, 64, 0, stream>>>(d_in[1], flags);
    // CPE: N/4 node-groups x 16 channel-quads
    cpe_kernel<<<(N_NODES / 4 * 16) / 256, 256, 0, stream>>>(x, cw, cb, hws);
    // Graph+head: 2048 persistent blocks, 2 uniform iterations each
    graph_head_kernel<int><<<2048, 256, 0, stream>>>(
        flags, hws, (const int*)d_in[1], gw, gb, ow, ob, out);
    graph_head_kernel<long long><<<2048, 256, 0, stream>>>(
        flags, hws, (const long long*)d_in[1], gw, gb, ow, ob, out);
}

// Round 11
// 403.859 us; speedup vs baseline: 1.6856x; 1.5067x over previous
//
#include <hip/hip_runtime.h>
#include <hip/hip_bf16.h>

#define N_NODES 262144
#define C_CH 64
#define K_NBR 16
#define NCLS 40

typedef unsigned short ushort_t;
typedef __attribute__((ext_vector_type(8))) short short8;
typedef __attribute__((ext_vector_type(4))) float floatx4;

__device__ __forceinline__ float bu2f(ushort_t u) {
    union { unsigned u32; float f; } v; v.u32 = ((unsigned)u) << 16; return v.f;
}
__device__ __forceinline__ ushort_t f2bu(float f) {
    union { float f; unsigned u; } v; v.f = f;
    unsigned r = v.u + 0x7FFFu + ((v.u >> 16) & 1u);
    return (ushort_t)(r >> 16);
}
__device__ __forceinline__ floatx4 bcast4(float g) {
    floatx4 v; v[0] = g; v[1] = g; v[2] = g; v[3] = g; return v;
}
__device__ __forceinline__ int ldi(const int* p, long i)       { return p[i]; }
__device__ __forceinline__ int ldi(const long long* p, long i) { return (int)p[i]; }

// ---------------- Sniffer: flags[1] = 1 if nbr is int64 ----------------------
__global__ void sniff_kernel(const void* __restrict__ nbr, int* __restrict__ flags) {
    int lane = threadIdx.x;                 // 64 threads
    const int* ni = (const int*)nbr;
    bool zodd = (ni[2 * lane + 1] == 0);    // int64 high words all zero
    unsigned long long mz = __ballot(zodd);
    if (lane == 0) flags[1] = (mz == ~0ULL) ? 1 : 0;
}

// ---------------- Kernel A: CPE depthwise conv3 + residual ------------------
// f32 x -> bf16 h table. One thread = 4 channels (float4) x 4 nodes.
__global__ void cpe_kernel(const float* __restrict__ x,
                           const float* __restrict__ cw,
                           const float* __restrict__ cb,
                           ushort_t* __restrict__ h) {
    int t  = blockIdx.x * 256 + threadIdx.x;   // [0, N/4 * 16)
    int ig = t >> 4;                           // node group (4 nodes)
    int cq = t & 15;                           // channel quad
    int i0 = ig << 2;
    int c0 = cq * 4;
    float w0[4], w1[4], w2[4], bb[4];
#pragma unroll
    for (int j = 0; j < 4; ++j) {
        w0[j] = cw[(c0 + j) * 3 + 0];
        w1[j] = cw[(c0 + j) * 3 + 1];
        w2[j] = cw[(c0 + j) * 3 + 2];
        bb[j] = cb[c0 + j];
    }
    float4 v[6];
#pragma unroll
    for (int r = 0; r < 6; ++r) {
        int i = i0 - 1 + r;
        if (i >= 0 && i < N_NODES) v[r] = *(const float4*)(x + (size_t)i * C_CH + c0);
        else                       v[r] = make_float4(0.f, 0.f, 0.f, 0.f);
    }
#pragma unroll
    for (int j = 0; j < 4; ++j) {
        float a[4] = {v[j].x, v[j].y, v[j].z, v[j].w};
        float b[4] = {v[j+1].x, v[j+1].y, v[j+1].z, v[j+1].w};
        float c[4] = {v[j+2].x, v[j+2].y, v[j+2].z, v[j+2].w};
        unsigned p0 = 0, p1 = 0;
#pragma unroll
        for (int q = 0; q < 4; ++q) {
            float r = b[q] + bb[q];
            r = fmaf(a[q], w0[q], r);
            r = fmaf(b[q], w1[q], r);
            r = fmaf(c[q], w2[q], r);
            unsigned u = (unsigned)f2bu(r);
            if (q < 2) p0 |= u << (q * 16);
            else       p1 |= u << ((q - 2) * 16);
        }
        *(uint2*)(h + (size_t)(i0 + j) * C_CH + c0) = make_uint2(p0, p1);
    }
}

// ---------------- Kernel G: standalone gather + max-rel ---------------------
// Latency-optimized: no LDS, one wave = 4 nodes in two 2-node batches
// (32 loads in flight), high occupancy. rel stored bf16, coalesced.
template <typename IT>
__global__ void __launch_bounds__(256, 4)
gather_kernel(const int* __restrict__ flags,
              const ushort_t* __restrict__ hws,
              const IT* __restrict__ nbr,
              ushort_t* __restrict__ relws) {
    if ((flags[1] != 0) != (sizeof(IT) == 8)) return;
    const int lane = threadIdx.x & 63;
    const int wid  = (blockIdx.x * 256 + threadIdx.x) >> 6;  // global wave id
    const int nb   = wid * 4;                                // 4 nodes per wave
    int idxv = ldi(nbr, (long)nb * K_NBR + lane);            // 4 rows x 16 nbrs
#pragma unroll
    for (int h = 0; h < 2; ++h) {
        float mx0 = -1e30f, mx1 = -1e30f;
#pragma unroll
        for (int k = 0; k < 16; ++k) {
            int j0 = __shfl(idxv, (h * 2 + 0) * 16 + k, 64);
            int j1 = __shfl(idxv, (h * 2 + 1) * 16 + k, 64);
            mx0 = fmaxf(mx0, bu2f(hws[((size_t)(unsigned)j0 << 6) + lane]));
            mx1 = fmaxf(mx1, bu2f(hws[((size_t)(unsigned)j1 << 6) + lane]));
        }
        float h0 = bu2f(hws[((size_t)(nb + h * 2 + 0) << 6) + lane]);
        float h1 = bu2f(hws[((size_t)(nb + h * 2 + 1) << 6) + lane]);
        relws[((size_t)(nb + h * 2 + 0) << 6) + lane] = f2bu(mx0 - h0);
        relws[((size_t)(nb + h * 2 + 1) << 6) + lane] = f2bu(mx1 - h1);
    }
}

// ---------------- Kernel B: MFMA proj/head + logsoftmax ---------------------
// DENSE=true: read h/rel rows coalesced from tables (split path).
// DENSE=false: r10 fused gather fallback (small-ws path).
template <bool DENSE, typename IT>
__global__ void __launch_bounds__(256, 4)
graph_head_kernel(const int* __restrict__ flags,
                  const ushort_t* __restrict__ hws,
                  const ushort_t* __restrict__ relws,
                  const IT* __restrict__ nbr,
                  const float* __restrict__ gw,
                  const float* __restrict__ gb,
                  const float* __restrict__ ow,
                  const float* __restrict__ ob,
                  float* __restrict__ out) {
    if (!DENSE) { if ((flags[1] != 0) != (sizeof(IT) == 8)) return; }

    __shared__ __align__(16) ushort_t sWt[64 * 136];       // 17408 B: W'[n][k], k=0..127
    __shared__ __align__(16) ushort_t sOt[48 * 72];        //  6912 B: O[n][k],  k=0..63
    __shared__ __align__(16) ushort_t sFeat[4][16 * 136];  // 17408 B: feat[m][0..127]
    __shared__ __align__(16) ushort_t sH2[4][16 * 88];     // 11264 B: h2 rows / logit stage

    // ---- stage transposed weights (once per block) ----
    for (int t = threadIdx.x; t < 64 * 128; t += 256) {
        int n = t >> 7, k = t & 127;
        float w = gw[k * C_CH + n];
        if (k == n) w += 1.0f;               // residual folded in: W' = W + [I;0]
        sWt[n * 136 + k] = f2bu(w);
    }
    for (int t = threadIdx.x; t < 48 * 64; t += 256) {
        int n = t >> 6, k = t & 63;
        float w = (n < NCLS) ? ow[k * NCLS + n] : 0.f;
        sOt[n * 72 + k] = f2bu(w);
    }
    __syncthreads();

    const int lane   = threadIdx.x & 63;
    const int wave   = threadIdx.x >> 6;
    const int lanelo = lane & 15;
    const int quad   = lane >> 4;

    float gbf[4];
#pragma unroll
    for (int nt = 0; nt < 4; ++nt) gbf[nt] = gb[nt * 16 + lanelo];
    float obf[3];
#pragma unroll
    for (int nt = 0; nt < 3; ++nt) {
        int n = nt * 16 + lanelo;
        obf[nt] = (n < NCLS) ? ob[n] : 0.f;
    }
    const bool ok2 = (lanelo < 8);   // n-tile 2 covers cols 32..47; valid n<40

    for (int g = blockIdx.x; g < (N_NODES >> 6); g += gridDim.x) {
        const int nb0 = g * 64 + wave * 16;
        ushort_t* feat = &sFeat[wave][0];
        ushort_t* h2w  = &sH2[wave][0];

        if constexpr (DENSE) {
            // ---- dense coalesced copy of h/rel rows into feat ----
            const ushort_t* src = (lane < 32) ? hws : relws;
            const int cc  = (lane & 31) * 2;
            const int off = (lane < 32) ? 0 : 64;
#pragma unroll
            for (int t = 0; t < 16; ++t) {
                unsigned v = *(const unsigned*)(src + ((size_t)(nb0 + t) << 6) + cc);
                *(unsigned*)(feat + t * 136 + off + cc) = v;
            }
        } else {
            // ---- fused gather + max-rel (fallback), lane = channel ----
#pragma unroll
            for (int q = 0; q < 4; ++q) {
                int idxv = ldi(nbr, (long)nb0 * K_NBR + q * 64 + lane);
#pragma unroll
                for (int tt = 0; tt < 4; ++tt) {
                    int t = q * 4 + tt;
                    ushort_t hu = hws[(size_t)(nb0 + t) * C_CH + lane];
                    float hif = bu2f(hu);
                    float mx = -1e30f;
#pragma unroll
                    for (int k = 0; k < 16; ++k) {
                        int j = __shfl(idxv, tt * 16 + k, 64);
                        mx = fmaxf(mx, bu2f(hws[((size_t)(unsigned)j << 6) + lane]));
                    }
                    feat[t * 136 + lane]      = hu;
                    feat[t * 136 + 64 + lane] = f2bu(mx - hif);
                }
            }
        }
        __syncthreads();

        // ---- proj: D[16x64] = feat[16x128] @ W' + gb ----
        floatx4 acc[4];
#pragma unroll
        for (int nt = 0; nt < 4; ++nt) acc[nt] = bcast4(gbf[nt]);
#pragma unroll
        for (int s = 0; s < 4; ++s) {
            short8 af = *(const short8*)(feat + lanelo * 136 + s * 32 + quad * 8);
#pragma unroll
            for (int nt = 0; nt < 4; ++nt) {
                short8 bf = *(const short8*)(sWt + (nt * 16 + lanelo) * 136 + s * 32 + quad * 8);
                acc[nt] = __builtin_amdgcn_mfma_f32_16x16x32_bf16(af, bf, acc[nt], 0, 0, 0);
            }
        }
#pragma unroll
        for (int nt = 0; nt < 4; ++nt)
#pragma unroll
            for (int r = 0; r < 4; ++r)
                h2w[(quad * 4 + r) * 88 + nt * 16 + lanelo] = f2bu(acc[nt][r]);
        __syncthreads();

        // ---- head: L[16x48] = h2[16x64] @ O (+ ob) ----
        floatx4 accH[3];
#pragma unroll
        for (int nt = 0; nt < 3; ++nt) accH[nt] = bcast4(obf[nt]);
#pragma unroll
        for (int s = 0; s < 2; ++s) {
            short8 hf = *(const short8*)(h2w + lanelo * 88 + s * 32 + quad * 8);
#pragma unroll
            for (int nt = 0; nt < 3; ++nt) {
                short8 bf = *(const short8*)(sOt + (nt * 16 + lanelo) * 72 + s * 32 + quad * 8);
                accH[nt] = __builtin_amdgcn_mfma_f32_16x16x32_bf16(hf, bf, accH[nt], 0, 0, 0);
            }
        }

        // ---- log-softmax per row; stage logits in LDS (reuse h2 region) ----
        float* fOut = (float*)h2w;
#pragma unroll
        for (int r = 0; r < 4; ++r) {
            float v0 = accH[0][r], v1 = accH[1][r];
            float v2 = ok2 ? accH[2][r] : -1e30f;
            float m = fmaxf(fmaxf(v0, v1), v2);
#pragma unroll
            for (int off = 1; off < 16; off <<= 1) m = fmaxf(m, __shfl_xor(m, off, 64));
            float s = __expf(v0 - m) + __expf(v1 - m) + (ok2 ? __expf(v2 - m) : 0.f);
#pragma unroll
            for (int off = 1; off < 16; off <<= 1) s += __shfl_xor(s, off, 64);
            float li = m + __logf(s);
            int rowbase = (quad * 4 + r) * NCLS;
            fOut[rowbase + lanelo]      = v0 - li;
            fOut[rowbase + 16 + lanelo] = v1 - li;
            if (ok2) fOut[rowbase + 32 + lanelo] = v2 - li;
        }
        __syncthreads();

        // ---- flat coalesced write: 640 consecutive floats per wave ----
        float* obase = out + (size_t)nb0 * NCLS;
#pragma unroll
        for (int k = 0; k < 10; ++k)
            obase[k * 64 + lane] = fOut[k * 64 + lane];
    }
}

extern "C" void kernel_launch(void* const* d_in, const int* in_sizes, int n_in,
                              void* d_out, int out_size, void* d_ws, size_t ws_size,
                              hipStream_t stream) {
    const float* x  = (const float*)d_in[0];
    const float* cw = (const float*)d_in[2];
    const float* cb = (const float*)d_in[3];
    const float* gw = (const float*)d_in[4];
    const float* gb = (const float*)d_in[5];
    const float* ow = (const float*)d_in[6];
    const float* ob = (const float*)d_in[7];
    float* out = (float*)d_out;

    int* flags = (int*)d_ws;
    ushort_t* hws   = (ushort_t*)((char*)d_ws + 1024);              // 32 MB
    ushort_t* relws = (ushort_t*)((char*)d_ws + 1024 + 33554432);   // 32 MB

    const bool split = (ws_size >= (size_t)(1024 + 2 * 33554432ULL));

    sniff_kernel<<<1, 64, 0, stream>>>(d_in[1], flags);
    cpe_kernel<<<(N_NODES / 4 * 16) / 256, 256, 0, stream>>>(x, cw, cb, hws);

    if (split) {
        // latency-optimized gather: 16384 blocks, 4 nodes/wave
        gather_kernel<int><<<N_NODES / 16, 256, 0, stream>>>(
            flags, hws, (const int*)d_in[1], relws);
        gather_kernel<long long><<<N_NODES / 16, 256, 0, stream>>>(
            flags, hws, (const long long*)d_in[1], relws);
        // dense MFMA pipeline: 4096 blocks, 1 group each
        graph_head_kernel<true, int><<<N_NODES / 64, 256, 0, stream>>>(
            flags, hws, relws, (const int*)d_in[1], gw, gb, ow, ob, out);
    } else {
        // fallback: fused gather (round-10 path)
        graph_head_kernel<false, int><<<2048, 256, 0, stream>>>(
            flags, hws, relws, (const int*)d_in[1], gw, gb, ow, ob, out);
        graph_head_kernel<false, long long><<<2048, 256, 0, stream>>>(
            flags, hws, relws, (const long long*)d_in[1], gw, gb, ow, ob, out);
    }
}

// Round 12
// 298.302 us; speedup vs baseline: 2.2821x; 1.3539x over previous
//
#include <hip/hip_runtime.h>
#include <hip/hip_bf16.h>

#define N_NODES 262144
#define C_CH 64
#define K_NBR 16
#define NCLS 40

typedef unsigned short ushort_t;
typedef __attribute__((ext_vector_type(8))) short short8;
typedef __attribute__((ext_vector_type(4))) float floatx4;

__device__ __forceinline__ float bu2f(ushort_t u) {
    union { unsigned u32; float f; } v; v.u32 = ((unsigned)u) << 16; return v.f;
}
__device__ __forceinline__ ushort_t f2bu(float f) {
    union { float f; unsigned u; } v; v.f = f;
    unsigned r = v.u + 0x7FFFu + ((v.u >> 16) & 1u);
    return (ushort_t)(r >> 16);
}
__device__ __forceinline__ floatx4 bcast4(float g) {
    floatx4 v; v[0] = g; v[1] = g; v[2] = g; v[3] = g; return v;
}
__device__ __forceinline__ int ldi(const int* p, long i)       { return p[i]; }
__device__ __forceinline__ int ldi(const long long* p, long i) { return (int)p[i]; }

// ---------------- Sniffer: flags[1] = 1 if nbr is int64 ----------------------
__global__ void sniff_kernel(const void* __restrict__ nbr, int* __restrict__ flags) {
    int lane = threadIdx.x;                 // 64 threads
    const int* ni = (const int*)nbr;
    bool zodd = (ni[2 * lane + 1] == 0);    // int64 high words all zero
    unsigned long long mz = __ballot(zodd);
    if (lane == 0) flags[1] = (mz == ~0ULL) ? 1 : 0;
}

// ---------------- Kernel A: CPE depthwise conv3 + residual ------------------
// f32 x -> bf16 h table. One thread = 4 channels (float4) x 4 nodes.
__global__ void cpe_kernel(const float* __restrict__ x,
                           const float* __restrict__ cw,
                           const float* __restrict__ cb,
                           ushort_t* __restrict__ h) {
    int t  = blockIdx.x * 256 + threadIdx.x;   // [0, N/4 * 16)
    int ig = t >> 4;                           // node group (4 nodes)
    int cq = t & 15;                           // channel quad
    int i0 = ig << 2;
    int c0 = cq * 4;
    float w0[4], w1[4], w2[4], bb[4];
#pragma unroll
    for (int j = 0; j < 4; ++j) {
        w0[j] = cw[(c0 + j) * 3 + 0];
        w1[j] = cw[(c0 + j) * 3 + 1];
        w2[j] = cw[(c0 + j) * 3 + 2];
        bb[j] = cb[c0 + j];
    }
    float4 v[6];
#pragma unroll
    for (int r = 0; r < 6; ++r) {
        int i = i0 - 1 + r;
        if (i >= 0 && i < N_NODES) v[r] = *(const float4*)(x + (size_t)i * C_CH + c0);
        else                       v[r] = make_float4(0.f, 0.f, 0.f, 0.f);
    }
#pragma unroll
    for (int j = 0; j < 4; ++j) {
        float a[4] = {v[j].x, v[j].y, v[j].z, v[j].w};
        float b[4] = {v[j+1].x, v[j+1].y, v[j+1].z, v[j+1].w};
        float c[4] = {v[j+2].x, v[j+2].y, v[j+2].z, v[j+2].w};
        unsigned p0 = 0, p1 = 0;
#pragma unroll
        for (int q = 0; q < 4; ++q) {
            float r = b[q] + bb[q];
            r = fmaf(a[q], w0[q], r);
            r = fmaf(b[q], w1[q], r);
            r = fmaf(c[q], w2[q], r);
            unsigned u = (unsigned)f2bu(r);
            if (q < 2) p0 |= u << (q * 16);
            else       p1 |= u << ((q - 2) * 16);
        }
        *(uint2*)(h + (size_t)(i0 + j) * C_CH + c0) = make_uint2(p0, p1);
    }
}

// ---------------- Kernel G: standalone gather + max-rel ---------------------
// MLP-optimized: per node, all 16 row-loads issued into a register batch
// (16 outstanding per wave) before the fmax tree. One wave = 4 nodes.
template <typename IT>
__global__ void __launch_bounds__(256, 8)
gather_kernel(const int* __restrict__ flags,
              const ushort_t* __restrict__ hws,
              const IT* __restrict__ nbr,
              ushort_t* __restrict__ relws) {
    if ((flags[1] != 0) != (sizeof(IT) == 8)) return;
    const int lane = threadIdx.x & 63;
    const int wid  = (blockIdx.x * 256 + threadIdx.x) >> 6;  // global wave id
    const int nb   = wid * 4;                                // 4 nodes per wave
    const ushort_t* hl = hws + lane;                         // per-lane base
    int idxv = ldi(nbr, (long)nb * K_NBR + lane);            // 4 rows x 16 nbrs
#pragma unroll
    for (int t = 0; t < 4; ++t) {
        unsigned off[16];
#pragma unroll
        for (int k = 0; k < 16; ++k)
            off[k] = ((unsigned)__shfl(idxv, t * 16 + k, 64)) << 6;
        float v[16];
#pragma unroll
        for (int k = 0; k < 16; ++k)                 // 16 independent loads
            v[k] = bu2f(hl[(size_t)off[k]]);
#pragma unroll
        for (int s = 8; s; s >>= 1)                  // fmax tree
#pragma unroll
            for (int k = 0; k < s; ++k)
                v[k] = fmaxf(v[k], v[k + s]);
        float hv = bu2f(hl[(size_t)(unsigned)(nb + t) << 6]);
        relws[((size_t)(nb + t) << 6) + lane] = f2bu(v[0] - hv);
    }
}

// ---------------- Kernel B: MFMA proj/head + logsoftmax ---------------------
// DENSE=true: A-fragments read DIRECTLY from h/rel tables (row layout == A
// layout), no sFeat staging. DENSE=false: r10 fused fallback (small ws).
template <bool DENSE, typename IT>
__global__ void __launch_bounds__(256, 4)
graph_head_kernel(const int* __restrict__ flags,
                  const ushort_t* __restrict__ hws,
                  const ushort_t* __restrict__ relws,
                  const IT* __restrict__ nbr,
                  const float* __restrict__ gw,
                  const float* __restrict__ gb,
                  const float* __restrict__ ow,
                  const float* __restrict__ ob,
                  float* __restrict__ out) {
    if (!DENSE) { if ((flags[1] != 0) != (sizeof(IT) == 8)) return; }

    __shared__ __align__(16) ushort_t sWt[64 * 136];       // 17408 B: W'[n][k], k=0..127
    __shared__ __align__(16) ushort_t sOt[48 * 72];        //  6912 B: O[n][k],  k=0..63
    __shared__ __align__(16) ushort_t sFeat[DENSE ? 1 : 4][DENSE ? 16 : 16 * 136];
    __shared__ __align__(16) ushort_t sH2[4][16 * 88];     // 11264 B: h2 rows / logit stage
    // DENSE: ~35.6 KB -> 4 blocks/CU

    // ---- stage transposed weights (once per block) ----
    for (int t = threadIdx.x; t < 64 * 128; t += 256) {
        int n = t >> 7, k = t & 127;
        float w = gw[k * C_CH + n];
        if (k == n) w += 1.0f;               // residual folded in: W' = W + [I;0]
        sWt[n * 136 + k] = f2bu(w);
    }
    for (int t = threadIdx.x; t < 48 * 64; t += 256) {
        int n = t >> 6, k = t & 63;
        float w = (n < NCLS) ? ow[k * NCLS + n] : 0.f;
        sOt[n * 72 + k] = f2bu(w);
    }
    __syncthreads();

    const int lane   = threadIdx.x & 63;
    const int wave   = threadIdx.x >> 6;
    const int lanelo = lane & 15;
    const int quad   = lane >> 4;

    float gbf[4];
#pragma unroll
    for (int nt = 0; nt < 4; ++nt) gbf[nt] = gb[nt * 16 + lanelo];
    float obf[3];
#pragma unroll
    for (int nt = 0; nt < 3; ++nt) {
        int n = nt * 16 + lanelo;
        obf[nt] = (n < NCLS) ? ob[n] : 0.f;
    }
    const bool ok2 = (lanelo < 8);   // n-tile 2 covers cols 32..47; valid n<40

    for (int g = blockIdx.x; g < (N_NODES >> 6); g += gridDim.x) {
        const int nb0 = g * 64 + wave * 16;
        ushort_t* h2w = &sH2[wave][0];

        // ---- proj: D[16x64] = feat[16x128] @ W' + gb ----
        floatx4 acc[4];
#pragma unroll
        for (int nt = 0; nt < 4; ++nt) acc[nt] = bcast4(gbf[nt]);

        if constexpr (DENSE) {
#pragma unroll
            for (int s = 0; s < 4; ++s) {
                // A-frag directly from table: row nb0+lanelo, cols (s&1)*32 + quad*8 ..+8
                const ushort_t* tbl = (s < 2) ? hws : relws;
                short8 af = *(const short8*)(tbl + ((size_t)(nb0 + lanelo) << 6)
                                             + (s & 1) * 32 + quad * 8);
#pragma unroll
                for (int nt = 0; nt < 4; ++nt) {
                    short8 bf = *(const short8*)(sWt + (nt * 16 + lanelo) * 136 + s * 32 + quad * 8);
                    acc[nt] = __builtin_amdgcn_mfma_f32_16x16x32_bf16(af, bf, acc[nt], 0, 0, 0);
                }
            }
        } else {
            ushort_t* feat = &sFeat[wave][0];
#pragma unroll
            for (int q = 0; q < 4; ++q) {
                int idxv = ldi(nbr, (long)nb0 * K_NBR + q * 64 + lane);
#pragma unroll
                for (int tt = 0; tt < 4; ++tt) {
                    int t = q * 4 + tt;
                    ushort_t hu = hws[(size_t)(nb0 + t) * C_CH + lane];
                    float hif = bu2f(hu);
                    float mx = -1e30f;
#pragma unroll
                    for (int k = 0; k < 16; ++k) {
                        int j = __shfl(idxv, tt * 16 + k, 64);
                        mx = fmaxf(mx, bu2f(hws[((size_t)(unsigned)j << 6) + lane]));
                    }
                    feat[t * 136 + lane]      = hu;
                    feat[t * 136 + 64 + lane] = f2bu(mx - hif);
                }
            }
            __syncthreads();
#pragma unroll
            for (int s = 0; s < 4; ++s) {
                short8 af = *(const short8*)(feat + lanelo * 136 + s * 32 + quad * 8);
#pragma unroll
                for (int nt = 0; nt < 4; ++nt) {
                    short8 bf = *(const short8*)(sWt + (nt * 16 + lanelo) * 136 + s * 32 + quad * 8);
                    acc[nt] = __builtin_amdgcn_mfma_f32_16x16x32_bf16(af, bf, acc[nt], 0, 0, 0);
                }
            }
        }

#pragma unroll
        for (int nt = 0; nt < 4; ++nt)
#pragma unroll
            for (int r = 0; r < 4; ++r)
                h2w[(quad * 4 + r) * 88 + nt * 16 + lanelo] = f2bu(acc[nt][r]);
        __syncthreads();

        // ---- head: L[16x48] = h2[16x64] @ O (+ ob) ----
        floatx4 accH[3];
#pragma unroll
        for (int nt = 0; nt < 3; ++nt) accH[nt] = bcast4(obf[nt]);
#pragma unroll
        for (int s = 0; s < 2; ++s) {
            short8 hf = *(const short8*)(h2w + lanelo * 88 + s * 32 + quad * 8);
#pragma unroll
            for (int nt = 0; nt < 3; ++nt) {
                short8 bf = *(const short8*)(sOt + (nt * 16 + lanelo) * 72 + s * 32 + quad * 8);
                accH[nt] = __builtin_amdgcn_mfma_f32_16x16x32_bf16(hf, bf, accH[nt], 0, 0, 0);
            }
        }

        // ---- log-softmax per row; stage logits in LDS (reuse h2 region) ----
        float* fOut = (float*)h2w;
#pragma unroll
        for (int r = 0; r < 4; ++r) {
            float v0 = accH[0][r], v1 = accH[1][r];
            float v2 = ok2 ? accH[2][r] : -1e30f;
            float m = fmaxf(fmaxf(v0, v1), v2);
#pragma unroll
            for (int off = 1; off < 16; off <<= 1) m = fmaxf(m, __shfl_xor(m, off, 64));
            float s = __expf(v0 - m) + __expf(v1 - m) + (ok2 ? __expf(v2 - m) : 0.f);
#pragma unroll
            for (int off = 1; off < 16; off <<= 1) s += __shfl_xor(s, off, 64);
            float li = m + __logf(s);
            int rowbase = (quad * 4 + r) * NCLS;
            fOut[rowbase + lanelo]      = v0 - li;
            fOut[rowbase + 16 + lanelo] = v1 - li;
            if (ok2) fOut[rowbase + 32 + lanelo] = v2 - li;
        }
        __syncthreads();

        // ---- flat coalesced write: 640 consecutive floats per wave ----
        float* obase = out + (size_t)nb0 * NCLS;
#pragma unroll
        for (int k = 0; k < 10; ++k)
            obase[k * 64 + lane] = fOut[k * 64 + lane];
    }
}

extern "C" void kernel_launch(void* const* d_in, const int* in_sizes, int n_in,
                              void* d_out, int out_size, void* d_ws, size_t ws_size,
                              hipStream_t stream) {
    const float* x  = (const float*)d_in[0];
    const float* cw = (const float*)d_in[2];
    const float* cb = (const float*)d_in[3];
    const float* gw = (const float*)d_in[4];
    const float* gb = (const float*)d_in[5];
    const float* ow = (const float*)d_in[6];
    const float* ob = (const float*)d_in[7];
    float* out = (float*)d_out;

    int* flags = (int*)d_ws;
    ushort_t* hws   = (ushort_t*)((char*)d_ws + 1024);              // 32 MB
    ushort_t* relws = (ushort_t*)((char*)d_ws + 1024 + 33554432);   // 32 MB

    const bool split = (ws_size >= (size_t)(1024 + 2 * 33554432ULL));

    sniff_kernel<<<1, 64, 0, stream>>>(d_in[1], flags);
    cpe_kernel<<<(N_NODES / 4 * 16) / 256, 256, 0, stream>>>(x, cw, cb, hws);

    if (split) {
        // MLP-optimized gather: 16384 blocks, 4 nodes/wave
        gather_kernel<int><<<N_NODES / 16, 256, 0, stream>>>(
            flags, hws, (const int*)d_in[1], relws);
        gather_kernel<long long><<<N_NODES / 16, 256, 0, stream>>>(
            flags, hws, (const long long*)d_in[1], relws);
        // dense MFMA pipeline: 4096 blocks, 1 group each
        graph_head_kernel<true, int><<<N_NODES / 64, 256, 0, stream>>>(
            flags, hws, relws, (const int*)d_in[1], gw, gb, ow, ob, out);
    } else {
        // fallback: fused gather (round-10 path)
        graph_head_kernel<false, int><<<2048, 256, 0, stream>>>(
            flags, hws, relws, (const int*)d_in[1], gw, gb, ow, ob, out);
        graph_head_kernel<false, long long><<<2048, 256, 0, stream>>>(
            flags, hws, relws, (const long long*)d_in[1], gw, gb, ow, ob, out);
    }
}